// Round 7
// baseline (156.108 us; speedup 1.0000x reference)
//
#include <hip/hip_runtime.h>
#include <math.h>

#define NODES 64
#define NSTEPS 64
#define EPG 1024
#define NTHREADS 256
#define NBLOCKS 256

typedef _Float16 f16;
typedef f16 f16x8 __attribute__((ext_vector_type(8)));
typedef f16 f16x4 __attribute__((ext_vector_type(4)));
typedef float f32x4 __attribute__((ext_vector_type(4)));

// ---- LDS regions (byte offsets) ----
#define R_WZ    0        // setup: Wt f16 [64 c][304 K] = 38912 ; scan: Zt f16 [64 t][64 n][4] = 32768 ; ph3: sLgG/sT1g/sT2g
#define R_M     38912    // setup: M1/M2/M3 row-major [64][72] f16 (9216 each) ; scan: Y private [4 w][6 g][64 lane][16B] = 24576
#define R_MT    66560    // setup: M1T @66560, M2T @75776 ([64][72] f16)
#define R_H     84992    // scan: buf0 {hT@+0 (8192), h@+8192}, buf1 {hT@+16384, h@+24576}  (32768 total)
#define R_XT    117760   // setup: X^T [64][72] f16
#define R_LGF   126976   // setup: f32 [64][64] Laplacian scratch
#define R_DEG   143360
#define R_DINV  143616
#define R_BSUM  143872
#define R_LOGIT 144128
#define SMEM_BYTES 144384

__device__ __forceinline__ f32x4 mfma16(f16x8 a, f16x8 b, f32x4 c) {
  return __builtin_amdgcn_mfma_f32_16x16x32_f16(a, b, c, 0, 0, 0);
}

#if __has_builtin(__builtin_amdgcn_mfma_f32_16x16x16f16)
#define HAVE_MFMA_K16 1
__device__ __forceinline__ f32x4 mfma16k16(f16x4 a, f16x4 b, f32x4 c) {
  return __builtin_amdgcn_mfma_f32_16x16x16f16(a, b, c, 0, 0, 0);
}
#else
#define HAVE_MFMA_K16 0
#endif

// setup: D[i][j] = sum_m A[rb*16+i][m] * B[cb*16+j][m], strides 72
__device__ __forceinline__ f32x4 mm64t(const f16* __restrict__ A, const f16* __restrict__ B,
                                       int rb, int cb, int lrow, int lk)
{
  f32x4 d = (f32x4){0.f, 0.f, 0.f, 0.f};
#pragma unroll
  for (int ch = 0; ch < 2; ++ch) {
    const f16x8 a = *(const f16x8*)(A + (rb * 16 + lrow) * 72 + ch * 32 + lk * 8);
    const f16x8 b = *(const f16x8*)(B + (cb * 16 + lrow) * 72 + ch * 32 + lk * 8);
    d = mfma16(a, b, d);
  }
  return d;
}

// fp32 4x4-tile matmul (phase 3)
template<int K>
__device__ __forceinline__ void mm4x4_acc(float acc[4][4],
                                          const float* __restrict__ A, int lda, int arow,
                                          const float* __restrict__ Bm, int ldb, int j4)
{
#pragma unroll 2
  for (int kc = 0; kc < K; kc += 4) {
    float av[4][4];
    float bv[4][4];
#pragma unroll
    for (int rr = 0; rr < 4; ++rr) {
      const float4 t = *(const float4*)(A + (arow + rr) * lda + kc);
      av[rr][0] = t.x; av[rr][1] = t.y; av[rr][2] = t.z; av[rr][3] = t.w;
    }
#pragma unroll
    for (int kk = 0; kk < 4; ++kk) {
      const float4 t = *(const float4*)(Bm + (kc + kk) * ldb + j4);
      bv[kk][0] = t.x; bv[kk][1] = t.y; bv[kk][2] = t.z; bv[kk][3] = t.w;
    }
#pragma unroll
    for (int rr = 0; rr < 4; ++rr)
#pragma unroll
      for (int cc = 0; cc < 4; ++cc) {
        float s = acc[rr][cc];
#pragma unroll
        for (int kk = 0; kk < 4; ++kk) s += av[rr][kk] * bv[kk][cc];
        acc[rr][cc] = s;
      }
  }
}

__global__ __launch_bounds__(NTHREADS, 1)
void gcrnn_mfma5(const float* __restrict__ x,     // [16384][64]
                 const float* __restrict__ ew,    // [262144]
                 const float* __restrict__ wA,    // [4][1][64]
                 const float* __restrict__ bA,    // [64]
                 const float* __restrict__ wB,    // [4][64][64]
                 const float* __restrict__ bB,    // [64]
                 const float* __restrict__ w1,    // [64][64]
                 const float* __restrict__ b1,    // [64]
                 const float* __restrict__ w2,    // [64][32]
                 const float* __restrict__ b2,    // [32]
                 const float* __restrict__ wfc,   // [2048][4]
                 const float* __restrict__ bfc,   // [4]
                 const int* __restrict__ esrc,
                 const int* __restrict__ edst,
                 float* __restrict__ out)         // [256][4]
{
  __shared__ __align__(16) char smem[SMEM_BYTES];

  f16*   sWt   = (f16*)(smem + R_WZ);
  f16*   sZt   = (f16*)(smem + R_WZ);
  f16*   sM1   = (f16*)(smem + R_M);
  f16*   sM2   = (f16*)(smem + R_M + 9216);
  f16*   sM3   = (f16*)(smem + R_M + 18432);
  f16*   sM1T  = (f16*)(smem + R_MT);
  f16*   sM2T  = (f16*)(smem + R_MT + 9216);
  f16*   sXT   = (f16*)(smem + R_XT);
  float* sLgF  = (float*)(smem + R_LGF);
  float* sDeg  = (float*)(smem + R_DEG);
  float* sDinv = (float*)(smem + R_DINV);
  float* sBsum = (float*)(smem + R_BSUM);
  float* sLogit= (float*)(smem + R_LOGIT);

  const int b = blockIdx.x, tid = threadIdx.x;
  const int gbase = b * NODES, ebase = b * EPG;
  const int wid = tid >> 6, lane = tid & 63;
  const int lrow = lane & 15, lk = lane >> 4;

  // ---------------- Setup stage 1: stage Wt, XT, biases; zero LGF ----------------
  for (int idx = tid; idx < 4096; idx += NTHREADS) sLgF[idx] = 0.f;
  if (tid < 64) { sDeg[tid] = 0.f; sBsum[tid] = bA[tid] + bB[tid]; }
  // Wt [c][K=304]: 0..255 = wB (K=64k+j), 256..259 = wA, 260..303 = 0
  for (int idx = tid; idx < 64 * 260; idx += NTHREADS) {
    const int k = idx >> 6, c = idx & 63;
    const float v = (k < 256) ? wB[(k >> 6) * 4096 + (k & 63) * 64 + c]
                              : wA[(k - 256) * 64 + c];
    sWt[c * 304 + k] = (f16)v;
  }
  for (int idx = tid; idx < 64 * 44; idx += NTHREADS) {
    const int c = idx / 44, j = idx - c * 44;
    sWt[c * 304 + 260 + j] = (f16)0.f;
  }
  // X^T: sXT[t*72+n] = x[gbase+n][t]
  for (int idx = tid; idx < 4096; idx += NTHREADS) {
    const int n = idx >> 6, t = idx & 63;
    sXT[t * 72 + n] = (f16)x[gbase * 64 + idx];
  }
  __syncthreads();

  // ---------------- Laplacian build ----------------
  for (int e = tid; e < EPG; e += NTHREADS)
    atomicAdd(&sDeg[esrc[ebase + e] - gbase], ew[ebase + e]);
  __syncthreads();
  if (tid < 64) { const float d = sDeg[tid]; sDinv[tid] = (d > 0.f) ? rsqrtf(d) : 0.f; }
  __syncthreads();
  for (int e = tid; e < EPG; e += NTHREADS) {
    const int sl = esrc[ebase + e] - gbase, dl = edst[ebase + e] - gbase;
    atomicAdd(&sLgF[dl * 64 + sl], -(sDinv[sl] * ew[ebase + e] * sDinv[dl]));
  }
  __syncthreads();

  // ---------------- stage M1/M1T ; preload W-frags (Wt dead after this) ----------------
  f16x8 Wfrag[4][9];
  float bsrv[4];
  for (int idx = tid; idx < 4096; idx += NTHREADS) {
    const int i = idx >> 6, j = idx & 63;
    const f16 v = (f16)sLgF[idx];
    sM1[i * 72 + j] = v;
    sM1T[j * 72 + i] = v;
  }
#pragma unroll
  for (int cb = 0; cb < 4; ++cb) {
#pragma unroll
    for (int j = 0; j < 9; ++j)
      Wfrag[cb][j] = *(const f16x8*)(sWt + (cb * 16 + lrow) * 304 + j * 32 + lk * 8);
    bsrv[cb] = sBsum[cb * 16 + lrow];
  }
  __syncthreads();

  // ---------------- W5: M2 (both layouts) + Z1 + Z slot0 ----------------
#pragma unroll
  for (int cbS = 0; cbS < 4; ++cbS) {
    f32x4 d;
    d = mm64t(sM1T, sM1, wid, cbS, lrow, lk);     // D[p][q] = Lam^2[q][p]
    {
      const int p0 = wid * 16 + lk * 4, q = cbS * 16 + lrow;
      f16x4 w;
#pragma unroll
      for (int r = 0; r < 4; ++r) w[r] = (f16)(2.f * d[r] - ((p0 + r) == q ? 1.f : 0.f));
      *(f16x4*)(sM2 + q * 72 + p0) = w;           // M2 row-major
    }
    d = mm64t(sM1, sM1T, wid, cbS, lrow, lk);     // Lam^2[p][q]
    {
      const int p0 = wid * 16 + lk * 4, q = cbS * 16 + lrow;
      f16x4 w;
#pragma unroll
      for (int r = 0; r < 4; ++r) w[r] = (f16)(2.f * d[r] - ((p0 + r) == q ? 1.f : 0.f));
      *(f16x4*)(sM2T + q * 72 + p0) = w;          // M2^T
    }
    d = mm64t(sM1, sXT, wid, cbS, lrow, lk);      // Z1[n=p][t=q]
    {
      const int p0 = wid * 16 + lk * 4, q = cbS * 16 + lrow;
#pragma unroll
      for (int r = 0; r < 4; ++r) sZt[q * 256 + (p0 + r) * 4 + 1] = (f16)d[r];
    }
  }
  for (int idx = tid; idx < 4096; idx += NTHREADS) {
    const int t = idx >> 6, n = idx & 63;
    sZt[(t * 64 + n) * 4 + 0] = sXT[t * 72 + n];
  }
  __syncthreads();

  // ---------------- W6: M3 + Z2 ----------------
#pragma unroll
  for (int cbS = 0; cbS < 4; ++cbS) {
    f32x4 d;
    d = mm64t(sM2T, sM1, wid, cbS, lrow, lk);     // D[p][q] = (Lam M2)[q][p]
    {
      const int p0 = wid * 16 + lk * 4, q = cbS * 16 + lrow;
      const f16x4 lv = *(const f16x4*)(sM1 + q * 72 + p0);
      f16x4 w;
#pragma unroll
      for (int r = 0; r < 4; ++r) w[r] = (f16)(2.f * d[r] - (float)lv[r]);
      *(f16x4*)(sM3 + q * 72 + p0) = w;           // M3 row-major
    }
    d = mm64t(sM2, sXT, wid, cbS, lrow, lk);      // Z2[n][t]
    {
      const int p0 = wid * 16 + lk * 4, q = cbS * 16 + lrow;
#pragma unroll
      for (int r = 0; r < 4; ++r) sZt[q * 256 + (p0 + r) * 4 + 2] = (f16)d[r];
    }
  }
  __syncthreads();

  // ---------------- W7: Z3 ----------------
#pragma unroll
  for (int cbS = 0; cbS < 4; ++cbS) {
    f32x4 d = mm64t(sM3, sXT, wid, cbS, lrow, lk);
    const int p0 = wid * 16 + lk * 4, q = cbS * 16 + lrow;
#pragma unroll
    for (int r = 0; r < 4; ++r) sZt[q * 256 + (p0 + r) * 4 + 3] = (f16)d[r];
  }
  __syncthreads();

  // ---------------- Preload M-frags ; zero h/hT buf0 ----------------
  f16x8 Mfrag[3][2];   // A-frags of M_k[strip wid]
#pragma unroll
  for (int k = 0; k < 3; ++k)
#pragma unroll
    for (int ch = 0; ch < 2; ++ch)
      Mfrag[k][ch] = *(const f16x8*)((const f16*)(smem + R_M + k * 9216) + (wid * 16 + lrow) * 72 + ch * 32 + lk * 8);
  f16x4 iF;
#pragma unroll
  for (int e = 0; e < 4; ++e) iF[e] = (f16)((lrow == lk * 4 + e) ? 1.f : 0.f);
  for (int idx = tid; idx < 4096; idx += NTHREADS)
    ((int*)(smem + R_H))[idx] = 0;    // hT buf0 + h buf0 (16384 B)
  __syncthreads();

  // ---------------- scan: 64 steps, ONE barrier each ----------------
  char* const Yb = smem + R_M + wid * 6144;   // private per-wave Y scratch
#pragma unroll 1
  for (int t = 0; t < NSTEPS; ++t) {
    const int cur = t & 1, nxt = cur ^ 1;
    const char* hTc = smem + R_H + cur * 16384;
    const char* hc  = smem + R_H + cur * 16384 + 8192;
    char* hTn = smem + R_H + nxt * 16384;
    char* hn  = smem + R_H + nxt * 16384 + 8192;

    // 1. hT B-frags (full h^T, frag-linear, conflict-free)
    f16x8 bT[4][2];
#pragma unroll
    for (int jt = 0; jt < 4; ++jt)
#pragma unroll
      for (int ch = 0; ch < 2; ++ch)
        bT[jt][ch] = *(const f16x8*)(hTc + ((jt * 2 + ch) * 64 + lane) * 16);

    // 2. Y_k[strip] = M_k @ h ; K16-transpose ; store A-layout to private scratch
#pragma unroll
    for (int k = 0; k < 3; ++k)
#pragma unroll
      for (int ft = 0; ft < 4; ++ft) {
        f32x4 d = mfma16(Mfrag[k][0], bT[ft][0], (f32x4){0.f, 0.f, 0.f, 0.f});
        d = mfma16(Mfrag[k][1], bT[ft][1], d);
        f16x4 yv;
#pragma unroll
        for (int r = 0; r < 4; ++r) yv[r] = (f16)d[r];
#if HAVE_MFMA_K16
        f32x4 dT = mfma16k16(yv, iF, (f32x4){0.f, 0.f, 0.f, 0.f});
        f16x4 yt;
#pragma unroll
        for (int r = 0; r < 4; ++r) yt[r] = (f16)dT[r];
        *(f16x4*)(Yb + ((k * 2 + (ft >> 1)) * 64 + lrow + 16 * ((ft & 1) * 2 + (lk >> 1))) * 16 + (lk & 1) * 8) = yt;
#else
#pragma unroll
        for (int r = 0; r < 4; ++r)
          ((f16*)Yb)[((k * 2 + (ft >> 1)) * 64 + (lk * 4 + r) + 16 * ((ft & 1) * 2 + (lrow >> 3))) * 8 + (lrow & 7)] = yv[r];
#endif
      }
    asm volatile("s_waitcnt lgkmcnt(0)" ::: "memory");   // intra-wave Y round trip

    // 3. pre = [h|Y1|Y2|Y3|z] @ Wcat + b  (all W-frags register-resident)
    const f16x8 a0 = *(const f16x8*)(hc + ((wid * 2 + 0) * 64 + lane) * 16);
    const f16x8 a1 = *(const f16x8*)(hc + ((wid * 2 + 1) * 64 + lane) * 16);
    f16x8 ayv[6];
#pragma unroll
    for (int g = 0; g < 6; ++g)
      ayv[g] = *(const f16x8*)(Yb + (g * 64 + lane) * 16);
    f16x8 az;
    {
      const f16x4 zv = *(const f16x4*)(smem + R_WZ + (t * 64 + wid * 16 + lrow) * 8);
      az[0] = zv[0]; az[1] = zv[1]; az[2] = zv[2]; az[3] = zv[3];
      az[4] = (f16)0.f; az[5] = (f16)0.f; az[6] = (f16)0.f; az[7] = (f16)0.f;
    }
    f32x4 acc[4];
#pragma unroll
    for (int cb = 0; cb < 4; ++cb) {
      acc[cb] = (f32x4){bsrv[cb], bsrv[cb], bsrv[cb], bsrv[cb]};
      acc[cb] = mfma16(a0, Wfrag[cb][0], acc[cb]);
      acc[cb] = mfma16(a1, Wfrag[cb][1], acc[cb]);
#pragma unroll
      for (int g = 0; g < 6; ++g)
        acc[cb] = mfma16(ayv[g], Wfrag[cb][2 + g], acc[cb]);
      acc[cb] = mfma16(az, Wfrag[cb][8], acc[cb]);
    }

    // 4. sigmoid + dual-layout h' stores (hT direct; h via K16 transpose)
#pragma unroll
    for (int cb = 0; cb < 4; ++cb) {
      f16x4 hv;
#pragma unroll
      for (int r = 0; r < 4; ++r) hv[r] = (f16)(1.f / (1.f + __expf(-acc[cb][r])));
      *(f16x4*)(hTn + ((cb * 2 + (wid >> 1)) * 64 + lrow + 16 * ((wid & 1) * 2 + (lk >> 1))) * 16 + (lk & 1) * 8) = hv;
#if HAVE_MFMA_K16
      f32x4 dT = mfma16k16(hv, iF, (f32x4){0.f, 0.f, 0.f, 0.f});
      f16x4 h2;
#pragma unroll
      for (int r = 0; r < 4; ++r) h2[r] = (f16)dT[r];
      *(f16x4*)(hn + ((wid * 2 + (cb >> 1)) * 64 + lrow + 16 * ((cb & 1) * 2 + (lk >> 1))) * 16 + (lk & 1) * 8) = h2;
#else
#pragma unroll
      for (int r = 0; r < 4; ++r)
        ((f16*)hn)[((wid * 2 + (cb >> 1)) * 64 + (lk * 4 + r) + 16 * ((cb & 1) * 2 + (lrow >> 3))) * 8 + (lrow & 7)] = hv[r];
#endif
    }
    __syncthreads();   // the ONE barrier: h(t+1) published
  }

  // ---------------- Phase 3: GCN x2 + FC + log_softmax (fp32) ----------------
  float* sLgG = (float*)(smem + 0);             // [64][68]
  float* sT1g = (float*)(smem + 17408);         // [64][68]
  float* sT2g = (float*)(smem + 34816);         // [64][68]
  const f16* hF = (const f16*)(smem + R_H + 8192);   // final h (buf0, frag-linear)

  for (int idx = tid; idx < 64 * 68; idx += NTHREADS) sLgG[idx] = 0.f;
  if (tid < 64) sDeg[tid] = 0.f;
  for (int idx = tid; idx < 4096; idx += NTHREADS) {
    const int n = idx >> 6, c = idx & 63;
    const f16 v = hF[(((n >> 4) * 2 + (c >> 5)) * 64 + (n & 15) + 16 * ((c >> 3) & 3)) * 8 + (c & 7)];
    sT1g[n * 68 + c] = (float)v;
  }
  if (tid < 4) sLogit[tid] = bfc[tid];
  __syncthreads();
  for (int e = tid; e < EPG; e += NTHREADS)
    atomicAdd(&sDeg[edst[ebase + e] - gbase], ew[ebase + e]);
  __syncthreads();
  if (tid < 64) sDinv[tid] = rsqrtf(sDeg[tid] + 1.f);
  __syncthreads();
  for (int e = tid; e < EPG; e += NTHREADS) {
    const int sl = esrc[ebase + e] - gbase, dl = edst[ebase + e] - gbase;
    atomicAdd(&sLgG[dl * 68 + sl], sDinv[sl] * ew[ebase + e] * sDinv[dl]);
  }
  __syncthreads();
  if (tid < 64) sLgG[tid * 68 + tid] += sDinv[tid] * sDinv[tid];
  __syncthreads();

  const int i4 = ((tid >> 4) & 15) * 4;
  const int j4 = (tid & 15) * 4;

  {                                             // xw1 = h @ w1 -> sT2g
    float m[4][4] = {};
    mm4x4_acc<64>(m, sT1g, 68, i4, w1, 64, j4);
#pragma unroll
    for (int rr = 0; rr < 4; ++rr)
      *(float4*)(sT2g + (i4 + rr) * 68 + j4) = make_float4(m[rr][0], m[rr][1], m[rr][2], m[rr][3]);
  }
  __syncthreads();
  {                                             // z1 = relu(Ag @ xw1 + b1) -> sT1g
    float m[4][4] = {};
    mm4x4_acc<64>(m, sLgG, 68, i4, sT2g, 68, j4);
#pragma unroll
    for (int rr = 0; rr < 4; ++rr) {
      float4 o;
      o.x = fmaxf(m[rr][0] + b1[j4 + 0], 0.f);
      o.y = fmaxf(m[rr][1] + b1[j4 + 1], 0.f);
      o.z = fmaxf(m[rr][2] + b1[j4 + 2], 0.f);
      o.w = fmaxf(m[rr][3] + b1[j4 + 3], 0.f);
      *(float4*)(sT1g + (i4 + rr) * 68 + j4) = o;
    }
  }
  __syncthreads();
  if (j4 < 32) {                                // xw2 = z1 @ w2 -> sT2g
    float m[4][4] = {};
    mm4x4_acc<64>(m, sT1g, 68, i4, w2, 32, j4);
#pragma unroll
    for (int rr = 0; rr < 4; ++rr)
      *(float4*)(sT2g + (i4 + rr) * 68 + j4) = make_float4(m[rr][0], m[rr][1], m[rr][2], m[rr][3]);
  }
  __syncthreads();
  if (j4 < 32) {                                // z2 = relu(Ag @ xw2 + b2) -> sT1g
    float m[4][4] = {};
    mm4x4_acc<64>(m, sLgG, 68, i4, sT2g, 68, j4);
#pragma unroll
    for (int rr = 0; rr < 4; ++rr) {
      float4 o;
      o.x = fmaxf(m[rr][0] + b2[j4 + 0], 0.f);
      o.y = fmaxf(m[rr][1] + b2[j4 + 1], 0.f);
      o.z = fmaxf(m[rr][2] + b2[j4 + 2], 0.f);
      o.w = fmaxf(m[rr][3] + b2[j4 + 3], 0.f);
      *(float4*)(sT1g + (i4 + rr) * 68 + j4) = o;
    }
  }
  __syncthreads();

  // FC + log_softmax
  float q0 = 0.f, q1 = 0.f, q2 = 0.f, q3 = 0.f;
  for (int f = tid; f < 2048; f += NTHREADS) {
    const int n = f >> 5, c = f & 31;
    const float v = sT1g[n * 68 + c];
    const float4 wv = *(const float4*)(wfc + f * 4);
    q0 += v * wv.x; q1 += v * wv.y; q2 += v * wv.z; q3 += v * wv.w;
  }
#pragma unroll
  for (int off = 1; off < 64; off <<= 1) {
    q0 += __shfl_xor(q0, off);
    q1 += __shfl_xor(q1, off);
    q2 += __shfl_xor(q2, off);
    q3 += __shfl_xor(q3, off);
  }
  if ((tid & 63) == 0) {
    atomicAdd(&sLogit[0], q0);
    atomicAdd(&sLogit[1], q1);
    atomicAdd(&sLogit[2], q2);
    atomicAdd(&sLogit[3], q3);
  }
  __syncthreads();
  if (tid == 0) {
    const float l0 = sLogit[0], l1 = sLogit[1], l2 = sLogit[2], l3 = sLogit[3];
    const float mx = fmaxf(fmaxf(l0, l1), fmaxf(l2, l3));
    const float s = expf(l0 - mx) + expf(l1 - mx) + expf(l2 - mx) + expf(l3 - mx);
    const float lse = mx + logf(s);
    out[b * 4 + 0] = l0 - lse;
    out[b * 4 + 1] = l1 - lse;
    out[b * 4 + 2] = l2 - lse;
    out[b * 4 + 3] = l3 - lse;
  }
}

extern "C" void kernel_launch(void* const* d_in, const int* in_sizes, int n_in,
                              void* d_out, int out_size, void* d_ws, size_t ws_size,
                              hipStream_t stream) {
  gcrnn_mfma5<<<NBLOCKS, NTHREADS, 0, stream>>>(
      (const float*)d_in[0],   // x
      (const float*)d_in[1],   // edge_weight
      (const float*)d_in[2],   // wA
      (const float*)d_in[3],   // bA
      (const float*)d_in[4],   // wB
      (const float*)d_in[5],   // bB
      (const float*)d_in[6],   // w1
      (const float*)d_in[7],   // b1
      (const float*)d_in[8],   // w2
      (const float*)d_in[9],   // b2
      (const float*)d_in[10],  // wfc
      (const float*)d_in[11],  // bfc
      (const int*)d_in[12],    // edge_src
      (const int*)d_in[13],    // edge_dst
      (float*)d_out);
}